// Round 3
// baseline (93.371 us; speedup 1.0000x reference)
//
#include <hip/hip_runtime.h>
#include <stdint.h>

// Problem constants (fixed shapes from the reference)
#define HEADS 8
#define DIM   512
#define HD    64
#define NE    16      // entities per sentence
#define NS    64      // sentences
#define NB    64      // batch

typedef short bf16x8 __attribute__((ext_vector_type(8)));
typedef float f32x4  __attribute__((ext_vector_type(4)));

__device__ __forceinline__ unsigned short f2bf(float f) {
    union { float f; uint32_t u; } v; v.f = f;
    uint32_t u = v.u;
    u += 0x7fffu + ((u >> 16) & 1u);   // RNE
    return (unsigned short)(u >> 16);
}

__device__ __forceinline__ void bar_lds() {
    // LDS-visibility barrier WITHOUT draining vmcnt (keeps DMA in flight)
    asm volatile("s_waitcnt lgkmcnt(0)" ::: "memory");
    __builtin_amdgcn_s_barrier();
}

// ---------------------------------------------------------------------------
// K0: fused prep.
//   blocks [0,64):    qvec[d] = q . wq[d] + bq[d]   (8 outputs/block, 32-lane K-split)
//   blocks [64,320):  wv -> bf16
//   blocks [320,576): wo -> bf16
// ---------------------------------------------------------------------------
__global__ __launch_bounds__(256) void k_prep(
    const float* __restrict__ qp, const float* __restrict__ wq,
    const float* __restrict__ bq, const float* __restrict__ wv,
    const float* __restrict__ wo, float* __restrict__ qvec,
    unsigned short* __restrict__ wv_bf, unsigned short* __restrict__ wo_bf)
{
    const int bid = blockIdx.x;
    const int t = threadIdx.x;
    if (bid < 64) {
        const int dl = t >> 5, js = t & 31;
        const int d = bid * 8 + dl;
        const float* w = wq + (size_t)d * DIM + js * 16;
        const float* q = qp + js * 16;
        float acc = 0.f;
        #pragma unroll
        for (int i = 0; i < 16; i++) acc += w[i] * q[i];
        #pragma unroll
        for (int msk = 16; msk >= 1; msk >>= 1) acc += __shfl_xor(acc, msk);
        if (js == 0) qvec[d] = acc + bq[d];
        return;
    }
    const bool is_v = bid < 320;
    const float* src = is_v ? wv : wo;
    unsigned short* dst = is_v ? wv_bf : wo_bf;
    const int li = ((is_v ? bid - 64 : bid - 320) * 1024 + t * 4);
    const float4 v = *(const float4*)(src + li);
    ushort4 hv;
    hv.x = f2bf(v.x); hv.y = f2bf(v.y); hv.z = f2bf(v.z); hv.w = f2bf(v.w);
    *(ushort4*)(dst + li) = hv;
}

// ---------------------------------------------------------------------------
// K1: u_f[h][c] = sum_{j<64} qvec[h*64+j] * wk[h*64+j][c]    (fp32 out)
//   64 blocks: h = bid>>3, 64-col group cg = bid&7. 1 wave each.
// q_h . bk_h is softmax-invariant -> bk unused.
// ---------------------------------------------------------------------------
__global__ __launch_bounds__(64) void k_uproj(
    const float* __restrict__ qvec, const float* __restrict__ wk,
    float* __restrict__ u_f)
{
    const int h = blockIdx.x >> 3, cg = blockIdx.x & 7;
    const int l = threadIdx.x;
    __shared__ float qs[HD];
    qs[l] = qvec[h * HD + l];
    __syncthreads();
    const int c = cg * 64 + l;
    const float* w = wk + (size_t)(h * HD) * DIM + c;
    float acc = 0.f;
    #pragma unroll 8
    for (int j = 0; j < HD; j++) acc += qs[j] * w[(size_t)j * DIM];
    u_f[h * DIM + c] = acc;
}

// ---------------------------------------------------------------------------
// DMA one tile (16 ents x 2 batch x 512 d, fp32 = 64KB) into LDS via
// global_load_lds. LDS layout is LINEAR in physical granule p (16B units):
//   p = (e*2+bb)*128 + jp,  logical granule j = jp ^ (e&7)  (source-swizzled)
// Each wave issues 16 instrs covering its contiguous 16KB quarter.
// ---------------------------------------------------------------------------
__device__ __forceinline__ void issue_tile_dma(
    const float* __restrict__ ents, float* lds_buf, int tau, int w, int lane)
{
    const int s = tau >> 5, bg = (tau & 31) << 1;
    #pragma unroll
    for (int i = 0; i < 16; i++) {
        const int p  = ((w * 16 + i) << 6) | lane;
        const int e  = p >> 8;
        const int bb = (p >> 7) & 1;
        const int jp = p & 127;
        const int j  = jp ^ (e & 7);
        const float* src = ents + ((((size_t)(s * NE + e)) * NB + (bg + bb)) << 9) + (j << 2);
        float* dst = lds_buf + ((w * 16 + i) << 8);   // 256 floats = 1KB per instr
        __builtin_amdgcn_global_load_lds(
            (const __attribute__((address_space(1))) void*)src,
            (__attribute__((address_space(3))) void*)dst, 16, 0, 0);
    }
}

// ---------------------------------------------------------------------------
// K2: fused score/softmax/weighted-aggregation, persistent + DMA double-buffer.
// 256 blocks x 8 tiles; tile = (s, 2 batch slots). All fp32.
//   score:    thread (bb,e,dpart): partial dots for all 8 h over d-range,
//             butterfly-reduce over dpart lanes, keep h = dpart.
//   softmax:  16 leader threads (bb,h) -> m, 1/sum; then 256 threads exp.
//   weighted: thread (bb,dchunk): acc[8h][4d] over 16 e; bf16-pack store.
// ---------------------------------------------------------------------------
__global__ __launch_bounds__(256, 1) void k_attn(
    const float* __restrict__ ents, const float* __restrict__ u_f,
    unsigned short* __restrict__ weighted)
{
    __shared__ float ent_s[2][16384];   // 2 x 64KB, physical-granule layout
    __shared__ float u_s[4096];         // 16KB, granule j ^ ((j>>4)&7)
    __shared__ float score_s[256];
    __shared__ float attn_s[256];       // [bb][e][h]
    __shared__ float m_s[16], inv_s[16];

    const int t = threadIdx.x;
    const int w = t >> 6, lane = t & 63;

    // stage u (swizzled), plain path — once per block
    #pragma unroll
    for (int r = 0; r < 4; r++) {
        const int g = t + 256 * r;           // 0..1023 granules
        const int h = g >> 7, j = g & 127;
        const int ju = j ^ ((j >> 4) & 7);
        const f32x4 v = *(const f32x4*)(u_f + g * 4);
        *(f32x4*)&u_s[((h << 7) | ju) << 2] = v;
    }
    __syncthreads();

    const int tau0 = blockIdx.x * 8;
    issue_tile_dma(ents, ent_s[0], tau0, w, lane);
    asm volatile("s_waitcnt vmcnt(0)" ::: "memory");
    __builtin_amdgcn_s_barrier();

    // thread decode (score / weighted mappings share bb)
    const int bb = t >> 7;
    const int e  = (t >> 3) & 15;
    const int dp = t & 7;
    const int dc = t & 127;
    const int ebase = ((e << 1) | bb) << 7;
    const int esw = e & 7;

    for (int it = 0; it < 8; ++it) {
        const int tau = tau0 + it;
        const int cur = it & 1;
        const float* buf = ent_s[cur];

        // prefetch next tile into the other buffer (stays in flight across barriers)
        if (it < 7) issue_tile_dma(ents, ent_s[cur ^ 1], tau + 1, w, lane);

        // ---- score: partial dots for all 8 heads over d in [dp*64, dp*64+64) ----
        float pt[8] = {0.f, 0.f, 0.f, 0.f, 0.f, 0.f, 0.f, 0.f};
        #pragma unroll
        for (int jj = 0; jj < 16; jj++) {
            const int jg = (dp << 4) | jj;
            const f32x4 ev = *(const f32x4*)&buf[(ebase | (jg ^ esw)) << 2];
            #pragma unroll
            for (int h = 0; h < 8; h++) {
                const f32x4 uv = *(const f32x4*)&u_s[((h << 7) | (jg ^ dp)) << 2];
                pt[h] += ev.x * uv.x + ev.y * uv.y + ev.z * uv.z + ev.w * uv.w;
            }
        }
        #pragma unroll
        for (int msk = 1; msk <= 4; msk <<= 1)
            #pragma unroll
            for (int h = 0; h < 8; h++) pt[h] += __shfl_xor(pt[h], msk);
        // keep h = dp (static select chain, no scratch)
        float sc = pt[0];
        #pragma unroll
        for (int h = 1; h < 8; h++) sc = (dp == h) ? pt[h] : sc;
        sc *= 0.125f;                       // 1/sqrt(64)
        score_s[t] = sc;
        bar_lds();

        // ---- softmax stats: 16 leaders (bb,h) ----
        if (t < 16) {
            const int lb = t >> 3, lh = t & 7;
            float mx = -1e30f;
            #pragma unroll
            for (int ee = 0; ee < 16; ee++)
                mx = fmaxf(mx, score_s[(((lb << 4) | ee) << 3) | lh]);
            float sum = 0.f;
            #pragma unroll
            for (int ee = 0; ee < 16; ee++)
                sum += __expf(score_s[(((lb << 4) | ee) << 3) | lh] - mx);
            m_s[t] = mx; inv_s[t] = 1.f / sum;
        }
        bar_lds();

        // ---- materialize attn (1 exp per thread) ----
        attn_s[t] = __expf(sc - m_s[(bb << 3) | dp]) * inv_s[(bb << 3) | dp];
        bar_lds();

        // ---- weighted sum: thread (bb, dc): 8 heads x float4 of d ----
        f32x4 acc0 = {0,0,0,0}, acc1 = {0,0,0,0}, acc2 = {0,0,0,0}, acc3 = {0,0,0,0};
        f32x4 acc4 = {0,0,0,0}, acc5 = {0,0,0,0}, acc6 = {0,0,0,0}, acc7 = {0,0,0,0};
        #pragma unroll
        for (int ee = 0; ee < 16; ee++) {
            const f32x4 ev = *(const f32x4*)&buf[((((ee << 1) | bb) << 7) | (dc ^ (ee & 7))) << 2];
            const f32x4 a0 = *(const f32x4*)&attn_s[((bb << 4) | ee) << 3];
            const f32x4 a1 = *(const f32x4*)&attn_s[(((bb << 4) | ee) << 3) + 4];
            acc0 += a0.x * ev; acc1 += a0.y * ev; acc2 += a0.z * ev; acc3 += a0.w * ev;
            acc4 += a1.x * ev; acc5 += a1.y * ev; acc6 += a1.z * ev; acc7 += a1.w * ev;
        }
        {
            const int s = tau >> 5, bg = (tau & 31) << 1;
            unsigned short* wrow = weighted + ((size_t)(s * NB + bg + bb) << 12) + (dc << 2);
            ushort4 o;
            o.x=f2bf(acc0.x); o.y=f2bf(acc0.y); o.z=f2bf(acc0.z); o.w=f2bf(acc0.w); *(ushort4*)(wrow + 0*DIM) = o;
            o.x=f2bf(acc1.x); o.y=f2bf(acc1.y); o.z=f2bf(acc1.z); o.w=f2bf(acc1.w); *(ushort4*)(wrow + 1*DIM) = o;
            o.x=f2bf(acc2.x); o.y=f2bf(acc2.y); o.z=f2bf(acc2.z); o.w=f2bf(acc2.w); *(ushort4*)(wrow + 2*DIM) = o;
            o.x=f2bf(acc3.x); o.y=f2bf(acc3.y); o.z=f2bf(acc3.z); o.w=f2bf(acc3.w); *(ushort4*)(wrow + 3*DIM) = o;
            o.x=f2bf(acc4.x); o.y=f2bf(acc4.y); o.z=f2bf(acc4.z); o.w=f2bf(acc4.w); *(ushort4*)(wrow + 4*DIM) = o;
            o.x=f2bf(acc5.x); o.y=f2bf(acc5.y); o.z=f2bf(acc5.z); o.w=f2bf(acc5.w); *(ushort4*)(wrow + 5*DIM) = o;
            o.x=f2bf(acc6.x); o.y=f2bf(acc6.y); o.z=f2bf(acc6.z); o.w=f2bf(acc6.w); *(ushort4*)(wrow + 6*DIM) = o;
            o.x=f2bf(acc7.x); o.y=f2bf(acc7.y); o.z=f2bf(acc7.z); o.w=f2bf(acc7.w); *(ushort4*)(wrow + 7*DIM) = o;
        }

        // ---- bottom: counted wait — drain the 16 DMA (oldest), leave stores ----
        if (it < 7) asm volatile("s_waitcnt vmcnt(8)" ::: "memory");
        __builtin_amdgcn_s_barrier();
    }
}

// ---------------------------------------------------------------------------
// K3/K4: C[M=4096, 64 cols per y] = A(bf16) @ B^T(bf16) + bias
// BM=64, BN=64, BK=64; 4 waves, each wave a 16-row strip x 64 cols.
// ---------------------------------------------------------------------------
template <typename CT>
__global__ __launch_bounds__(256) void k_gemm(
    const unsigned short* __restrict__ A, int lda, int aOffY,
    const unsigned short* __restrict__ B, int ldb, int bOffY,
    const float* __restrict__ bias, CT* __restrict__ C, int ldc, int cOffY, int K)
{
    __shared__ unsigned short a_s[64][72];
    __shared__ unsigned short b_s[64][72];
    const int t = threadIdx.x;
    const int m0 = blockIdx.x * 64;
    const int y  = blockIdx.y;
    const int w = t >> 6, l = t & 63;
    const int m = l & 15, g = l >> 4;
    const int lr = t >> 2, lk = (t & 3) * 16;

    const unsigned short* Ap = A + (size_t)(m0 + lr) * lda + (size_t)aOffY * y;
    const unsigned short* Bp = B + (size_t)(bOffY * y + lr) * ldb;

    f32x4 acc[4];
    #pragma unroll
    for (int i = 0; i < 4; i++) acc[i] = (f32x4){0.f, 0.f, 0.f, 0.f};

    for (int k0 = 0; k0 < K; k0 += 64) {
        const ushort4 av0 = *(const ushort4*)(Ap + k0 + lk);
        const ushort4 av1 = *(const ushort4*)(Ap + k0 + lk + 4);
        const ushort4 av2 = *(const ushort4*)(Ap + k0 + lk + 8);
        const ushort4 av3 = *(const ushort4*)(Ap + k0 + lk + 12);
        const ushort4 bv0 = *(const ushort4*)(Bp + k0 + lk);
        const ushort4 bv1 = *(const ushort4*)(Bp + k0 + lk + 4);
        const ushort4 bv2 = *(const ushort4*)(Bp + k0 + lk + 8);
        const ushort4 bv3 = *(const ushort4*)(Bp + k0 + lk + 12);
        *(ushort4*)&a_s[lr][lk]      = av0;
        *(ushort4*)&a_s[lr][lk + 4]  = av1;
        *(ushort4*)&a_s[lr][lk + 8]  = av2;
        *(ushort4*)&a_s[lr][lk + 12] = av3;
        *(ushort4*)&b_s[lr][lk]      = bv0;
        *(ushort4*)&b_s[lr][lk + 4]  = bv1;
        *(ushort4*)&b_s[lr][lk + 8]  = bv2;
        *(ushort4*)&b_s[lr][lk + 12] = bv3;
        __syncthreads();
        #pragma unroll
        for (int kk = 0; kk < 64; kk += 32) {
            const int kp = kk + g * 8;
            const bf16x8 af = *(const bf16x8*)&a_s[w * 16 + m][kp];
            const bf16x8 b0 = *(const bf16x8*)&b_s[ 0 + m][kp];
            const bf16x8 b1 = *(const bf16x8*)&b_s[16 + m][kp];
            const bf16x8 b2 = *(const bf16x8*)&b_s[32 + m][kp];
            const bf16x8 b3 = *(const bf16x8*)&b_s[48 + m][kp];
            acc[0] = __builtin_amdgcn_mfma_f32_16x16x32_bf16(af, b0, acc[0], 0, 0, 0);
            acc[1] = __builtin_amdgcn_mfma_f32_16x16x32_bf16(af, b1, acc[1], 0, 0, 0);
            acc[2] = __builtin_amdgcn_mfma_f32_16x16x32_bf16(af, b2, acc[2], 0, 0, 0);
            acc[3] = __builtin_amdgcn_mfma_f32_16x16x32_bf16(af, b3, acc[3], 0, 0, 0);
        }
        __syncthreads();
    }

    const int colbase = cOffY * y;
    #pragma unroll
    for (int nt = 0; nt < 4; nt++) {
        const int col = colbase + nt * 16 + m;
        const float bs = bias[col];
        #pragma unroll
        for (int j = 0; j < 4; j++) {
            const int row = m0 + w * 16 + g * 4 + j;
            const float val = acc[nt][j] + bs;
            if (sizeof(CT) == 2) {
                ((unsigned short*)C)[(size_t)row * ldc + col] = f2bf(val);
            } else {
                ((float*)C)[(size_t)row * ldc + col] = val;
            }
        }
    }
}

// ---------------------------------------------------------------------------
extern "C" void kernel_launch(void* const* d_in, const int* in_sizes, int n_in,
                              void* d_out, int out_size, void* d_ws, size_t ws_size,
                              hipStream_t stream)
{
    const float* ents = (const float*)d_in[0];
    const float* qp   = (const float*)d_in[1];
    const float* wq   = (const float*)d_in[2];
    const float* wk   = (const float*)d_in[3];
    const float* wv   = (const float*)d_in[4];
    const float* wo   = (const float*)d_in[5];
    const float* bq   = (const float*)d_in[6];
    // d_in[7] = bk: per-head softmax-invariant constant -> algebraically unused
    const float* bv   = (const float*)d_in[8];
    const float* bo   = (const float*)d_in[9];

    // workspace layout (~39.7 MB)
    char* ws = (char*)d_ws;
    float*          qvec     = (float*)ws;                                 // 2 KB
    float*          u_f      = (float*)(ws + 4096);                        // 16 KB [8][512]
    unsigned short* wv_bf    = (unsigned short*)(ws + 65536);              // 512 KB
    unsigned short* wo_bf    = (unsigned short*)(ws + 65536 + 524288);     // 512 KB
    unsigned short* weighted = (unsigned short*)(ws + 2097152);            // 32 MB [4096][4096]
    unsigned short* ctx      = (unsigned short*)(ws + 2097152 + 33554432); // 4 MB [4096][512]

    k_prep <<<576, 256, 0, stream>>>(qp, wq, bq, wv, wo, qvec, wv_bf, wo_bf);
    k_uproj<<<64, 64, 0, stream>>>(qvec, wk, u_f);
    k_attn <<<256, 256, 0, stream>>>(ents, u_f, weighted);
    k_gemm<unsigned short><<<dim3(64, 8), 256, 0, stream>>>(
        weighted, HEADS * DIM, DIM, wv_bf, DIM, HD, bv, ctx, DIM, HD, DIM);
    k_gemm<float><<<dim3(64, 8), 256, 0, stream>>>(
        ctx, DIM, 0, wo_bf, DIM, HD, bo, (float*)d_out, DIM, HD, DIM);
}

// Round 4
// 74.286 us; speedup vs baseline: 1.2569x; 1.2569x over previous
//
#include <hip/hip_runtime.h>
#include <stdint.h>

// Problem constants (fixed shapes from the reference)
#define HEADS 8
#define DIM   512
#define HD    64
#define NE    16      // entities per sentence
#define NS    64      // sentences
#define NB    64      // batch

typedef short bf16x8 __attribute__((ext_vector_type(8)));
typedef float f32x4  __attribute__((ext_vector_type(4)));

__device__ __forceinline__ unsigned short f2bf(float f) {
    union { float f; uint32_t u; } v; v.f = f;
    uint32_t u = v.u;
    u += 0x7fffu + ((u >> 16) & 1u);   // RNE
    return (unsigned short)(u >> 16);
}

// pack 8 fp32 -> bf16x8 via HW RNE converts (no builtin on gfx950 -> asm)
__device__ __forceinline__ bf16x8 cvt8(float4 lo, float4 hi) {
    union { uint32_t u[4]; bf16x8 v; } r;
    asm("v_cvt_pk_bf16_f32 %0, %1, %2" : "=v"(r.u[0]) : "v"(lo.x), "v"(lo.y));
    asm("v_cvt_pk_bf16_f32 %0, %1, %2" : "=v"(r.u[1]) : "v"(lo.z), "v"(lo.w));
    asm("v_cvt_pk_bf16_f32 %0, %1, %2" : "=v"(r.u[2]) : "v"(hi.x), "v"(hi.y));
    asm("v_cvt_pk_bf16_f32 %0, %1, %2" : "=v"(r.u[3]) : "v"(hi.z), "v"(hi.w));
    return r.v;
}

// ---------------------------------------------------------------------------
// K0: fused prep.
//   blocks [0,64):    qvec[d] = q . wq[d] + bq[d]   (8 outputs/block, 32-lane K-split)
//   blocks [64,320):  wv -> bf16
//   blocks [320,576): wo -> bf16
// ---------------------------------------------------------------------------
__global__ __launch_bounds__(256) void k_prep(
    const float* __restrict__ qp, const float* __restrict__ wq,
    const float* __restrict__ bq, const float* __restrict__ wv,
    const float* __restrict__ wo, float* __restrict__ qvec,
    unsigned short* __restrict__ wv_bf, unsigned short* __restrict__ wo_bf)
{
    const int bid = blockIdx.x;
    const int t = threadIdx.x;
    if (bid < 64) {
        const int dl = t >> 5, js = t & 31;
        const int d = bid * 8 + dl;
        const float* w = wq + (size_t)d * DIM + js * 16;
        const float* q = qp + js * 16;
        float acc = 0.f;
        #pragma unroll
        for (int i = 0; i < 16; i++) acc += w[i] * q[i];
        #pragma unroll
        for (int msk = 16; msk >= 1; msk >>= 1) acc += __shfl_xor(acc, msk);
        if (js == 0) qvec[d] = acc + bq[d];
        return;
    }
    const bool is_v = bid < 320;
    const float* src = is_v ? wv : wo;
    unsigned short* dst = is_v ? wv_bf : wo_bf;
    const int li = ((is_v ? bid - 64 : bid - 320) * 1024 + t * 4);
    const float4 v = *(const float4*)(src + li);
    ushort4 hv;
    hv.x = f2bf(v.x); hv.y = f2bf(v.y); hv.z = f2bf(v.z); hv.w = f2bf(v.w);
    *(ushort4*)(dst + li) = hv;
}

// ---------------------------------------------------------------------------
// K1: u_bf[h][c] = bf16( sum_{j<64} qvec[h*64+j] * wk[h*64+j][c] )
//   blocks [0,16): h = bid>>1, c = (bid&1)*256 + t   (coalesced over c per j)
//   blocks 16,17:  zero pad rows 8..15
// q_h . bk_h is softmax-invariant -> bk unused.
// ---------------------------------------------------------------------------
__global__ __launch_bounds__(256) void k_uproj(
    const float* __restrict__ qvec, const float* __restrict__ wk,
    unsigned short* __restrict__ u_bf)
{
    const int bid = blockIdx.x;
    const int t = threadIdx.x;
    if (bid >= 16) {                 // zero rows 8..15 (512 bf16 = 1KB each)
        const int row = 8 + (bid - 16) * 4 + (t >> 6);
        ((uint4*)(u_bf + row * DIM))[t & 63] = (uint4){0u, 0u, 0u, 0u};
        return;
    }
    const int h = bid >> 1;
    const int c = (bid & 1) * 256 + t;
    __shared__ float qs[HD];
    if (t < HD) qs[t] = qvec[h * HD + t];
    __syncthreads();
    const float* w = wk + (size_t)(h * HD) * DIM + c;
    float acc = 0.f;
    #pragma unroll 8
    for (int j = 0; j < HD; j++) acc += qs[j] * w[(size_t)j * DIM];
    u_bf[h * DIM + c] = f2bf(acc);
}

// ---------------------------------------------------------------------------
// K2: fused score/softmax/weighted-aggregation. One WAVE per (s,b).
// No block barriers, no big LDS. 1024 blocks x 4 waves = 4096 waves.
//   score:   MFMA 16x16x32 over fragments loaded straight from global
//            (fp32 -> bf16 in-reg); D layout: e = 4g+j, h = lane&15.
//   softmax: shuffle over e-groups; attn -> 512B per-wave LDS (same-wave).
//   weighted: lane owns d0 = 8*lane; re-read ent rows contiguously (L2/L3-hot),
//            fp32 FMA into acc[8h][8d]; bf16 store.
// ---------------------------------------------------------------------------
__global__ __launch_bounds__(256) void k_attn(
    const float* __restrict__ ents, const unsigned short* __restrict__ u_bf,
    unsigned short* __restrict__ weighted)
{
    __shared__ float attn_s[4][NE][8];   // 2 KB total
    const int t = threadIdx.x;
    const int w = t >> 6, lane = t & 63;
    // XCD-aware swizzle (1024 = 8*128, bijective): contiguous s-chunks per XCD
    const int bid = ((int)blockIdx.x & 7) * 128 + ((int)blockIdx.x >> 3);
    const int s = bid >> 4;
    const int b = ((bid & 15) << 2) | w;

    const int m = lane & 15, g = lane >> 4;

    // ---- score: 16 MFMA k-steps, A-fragments direct from global ----
    const float* aptr = ents + (((size_t)(s * NE + m)) * NB + b) * DIM + g * 8;
    const unsigned short* urow = u_bf + m * DIM + g * 8;
    f32x4 acc = {0.f, 0.f, 0.f, 0.f};
    #pragma unroll
    for (int ks = 0; ks < 16; ks++) {
        const float4 f0 = *(const float4*)(aptr + ks * 32);
        const float4 f1 = *(const float4*)(aptr + ks * 32 + 4);
        const bf16x8 af = cvt8(f0, f1);
        const bf16x8 bf = *(const bf16x8*)(urow + ks * 32);
        acc = __builtin_amdgcn_mfma_f32_16x16x32_bf16(af, bf, acc, 0, 0, 0);
    }

    // ---- softmax over e (rows live in regs j + lane>>4 groups) ----
    {
        const float scale = 0.125f;   // 1/sqrt(64)
        float s0 = acc[0]*scale, s1 = acc[1]*scale, s2 = acc[2]*scale, s3 = acc[3]*scale;
        float mx = fmaxf(fmaxf(s0, s1), fmaxf(s2, s3));
        mx = fmaxf(mx, __shfl_xor(mx, 16));
        mx = fmaxf(mx, __shfl_xor(mx, 32));
        const float p0 = __expf(s0 - mx), p1 = __expf(s1 - mx);
        const float p2 = __expf(s2 - mx), p3 = __expf(s3 - mx);
        float sm = p0 + p1 + p2 + p3;
        sm += __shfl_xor(sm, 16);
        sm += __shfl_xor(sm, 32);
        const float inv = 1.f / sm;
        if (m < HEADS) {             // h = m; only real heads stored
            attn_s[w][4 * g + 0][m] = p0 * inv;
            attn_s[w][4 * g + 1][m] = p1 * inv;
            attn_s[w][4 * g + 2][m] = p2 * inv;
            attn_s[w][4 * g + 3][m] = p3 * inv;
        }
    }
    // same-wave LDS dependency: compiler inserts lgkmcnt; no barrier needed.

    // ---- weighted sum: lane owns d0 = 8*lane, fp32 accumulation ----
    const int d0 = lane << 3;
    f32x4 accA[HEADS], accB[HEADS];
    #pragma unroll
    for (int h = 0; h < HEADS; h++) { accA[h] = (f32x4){0,0,0,0}; accB[h] = (f32x4){0,0,0,0}; }

    const float* erow = ents + (((size_t)(s * NE)) * NB + b) * DIM + d0;
    #pragma unroll
    for (int e = 0; e < NE; e++) {
        const float* ep = erow + (size_t)e * (NB * DIM);
        const f32x4 e0 = *(const f32x4*)(ep);
        const f32x4 e1 = *(const f32x4*)(ep + 4);
        const f32x4 a0 = *(const f32x4*)&attn_s[w][e][0];
        const f32x4 a1 = *(const f32x4*)&attn_s[w][e][4];
        accA[0] += a0.x * e0; accB[0] += a0.x * e1;
        accA[1] += a0.y * e0; accB[1] += a0.y * e1;
        accA[2] += a0.z * e0; accB[2] += a0.z * e1;
        accA[3] += a0.w * e0; accB[3] += a0.w * e1;
        accA[4] += a1.x * e0; accB[4] += a1.x * e1;
        accA[5] += a1.y * e0; accB[5] += a1.y * e1;
        accA[6] += a1.z * e0; accB[6] += a1.z * e1;
        accA[7] += a1.w * e0; accB[7] += a1.w * e1;
    }
    unsigned short* wrow = weighted + ((size_t)(s * NB + b) << 12) + d0;
    #pragma unroll
    for (int h = 0; h < HEADS; h++) {
        const bf16x8 ov = cvt8((float4){accA[h].x, accA[h].y, accA[h].z, accA[h].w},
                               (float4){accB[h].x, accB[h].y, accB[h].z, accB[h].w});
        *(bf16x8*)(wrow + h * DIM) = ov;
    }
}

// ---------------------------------------------------------------------------
// K3/K4: C[M=4096, 64 cols per y] = A(bf16) @ B^T(bf16) + bias
// BM=64, BN=64, BK=64; 4 waves, each wave a 16-row strip x 64 cols.
// ---------------------------------------------------------------------------
template <typename CT>
__global__ __launch_bounds__(256) void k_gemm(
    const unsigned short* __restrict__ A, int lda, int aOffY,
    const unsigned short* __restrict__ B, int ldb, int bOffY,
    const float* __restrict__ bias, CT* __restrict__ C, int ldc, int cOffY, int K)
{
    __shared__ unsigned short a_s[64][72];
    __shared__ unsigned short b_s[64][72];
    const int t = threadIdx.x;
    const int m0 = blockIdx.x * 64;
    const int y  = blockIdx.y;
    const int w = t >> 6, l = t & 63;
    const int m = l & 15, g = l >> 4;
    const int lr = t >> 2, lk = (t & 3) * 16;

    const unsigned short* Ap = A + (size_t)(m0 + lr) * lda + (size_t)aOffY * y;
    const unsigned short* Bp = B + (size_t)(bOffY * y + lr) * ldb;

    f32x4 acc[4];
    #pragma unroll
    for (int i = 0; i < 4; i++) acc[i] = (f32x4){0.f, 0.f, 0.f, 0.f};

    for (int k0 = 0; k0 < K; k0 += 64) {
        const ushort4 av0 = *(const ushort4*)(Ap + k0 + lk);
        const ushort4 av1 = *(const ushort4*)(Ap + k0 + lk + 4);
        const ushort4 av2 = *(const ushort4*)(Ap + k0 + lk + 8);
        const ushort4 av3 = *(const ushort4*)(Ap + k0 + lk + 12);
        const ushort4 bv0 = *(const ushort4*)(Bp + k0 + lk);
        const ushort4 bv1 = *(const ushort4*)(Bp + k0 + lk + 4);
        const ushort4 bv2 = *(const ushort4*)(Bp + k0 + lk + 8);
        const ushort4 bv3 = *(const ushort4*)(Bp + k0 + lk + 12);
        *(ushort4*)&a_s[lr][lk]      = av0;
        *(ushort4*)&a_s[lr][lk + 4]  = av1;
        *(ushort4*)&a_s[lr][lk + 8]  = av2;
        *(ushort4*)&a_s[lr][lk + 12] = av3;
        *(ushort4*)&b_s[lr][lk]      = bv0;
        *(ushort4*)&b_s[lr][lk + 4]  = bv1;
        *(ushort4*)&b_s[lr][lk + 8]  = bv2;
        *(ushort4*)&b_s[lr][lk + 12] = bv3;
        __syncthreads();
        #pragma unroll
        for (int kk = 0; kk < 64; kk += 32) {
            const int kp = kk + g * 8;
            const bf16x8 af = *(const bf16x8*)&a_s[w * 16 + m][kp];
            const bf16x8 b0 = *(const bf16x8*)&b_s[ 0 + m][kp];
            const bf16x8 b1 = *(const bf16x8*)&b_s[16 + m][kp];
            const bf16x8 b2 = *(const bf16x8*)&b_s[32 + m][kp];
            const bf16x8 b3 = *(const bf16x8*)&b_s[48 + m][kp];
            acc[0] = __builtin_amdgcn_mfma_f32_16x16x32_bf16(af, b0, acc[0], 0, 0, 0);
            acc[1] = __builtin_amdgcn_mfma_f32_16x16x32_bf16(af, b1, acc[1], 0, 0, 0);
            acc[2] = __builtin_amdgcn_mfma_f32_16x16x32_bf16(af, b2, acc[2], 0, 0, 0);
            acc[3] = __builtin_amdgcn_mfma_f32_16x16x32_bf16(af, b3, acc[3], 0, 0, 0);
        }
        __syncthreads();
    }

    const int colbase = cOffY * y;
    #pragma unroll
    for (int nt = 0; nt < 4; nt++) {
        const int col = colbase + nt * 16 + m;
        const float bs = bias[col];
        #pragma unroll
        for (int j = 0; j < 4; j++) {
            const int row = m0 + w * 16 + g * 4 + j;
            const float val = acc[nt][j] + bs;
            if (sizeof(CT) == 2) {
                ((unsigned short*)C)[(size_t)row * ldc + col] = f2bf(val);
            } else {
                ((float*)C)[(size_t)row * ldc + col] = val;
            }
        }
    }
}

// ---------------------------------------------------------------------------
extern "C" void kernel_launch(void* const* d_in, const int* in_sizes, int n_in,
                              void* d_out, int out_size, void* d_ws, size_t ws_size,
                              hipStream_t stream)
{
    const float* ents = (const float*)d_in[0];
    const float* qp   = (const float*)d_in[1];
    const float* wq   = (const float*)d_in[2];
    const float* wk   = (const float*)d_in[3];
    const float* wv   = (const float*)d_in[4];
    const float* wo   = (const float*)d_in[5];
    const float* bq   = (const float*)d_in[6];
    // d_in[7] = bk: per-head softmax-invariant constant -> algebraically unused
    const float* bv   = (const float*)d_in[8];
    const float* bo   = (const float*)d_in[9];

    // workspace layout (~40 MB)
    char* ws = (char*)d_ws;
    float*          qvec     = (float*)ws;                                 // 2 KB
    unsigned short* u_bf     = (unsigned short*)(ws + 4096);               // 16 KB [16][512]
    unsigned short* wv_bf    = (unsigned short*)(ws + 65536);              // 512 KB
    unsigned short* wo_bf    = (unsigned short*)(ws + 65536 + 524288);     // 512 KB
    unsigned short* weighted = (unsigned short*)(ws + 2097152);            // 32 MB [4096][4096]
    unsigned short* ctx      = (unsigned short*)(ws + 2097152 + 33554432); // 4 MB [4096][512]

    k_prep <<<576, 256, 0, stream>>>(qp, wq, bq, wv, wo, qvec, wv_bf, wo_bf);
    k_uproj<<<18, 256, 0, stream>>>(qvec, wk, u_bf);
    k_attn <<<1024, 256, 0, stream>>>(ents, u_bf, weighted);
    k_gemm<unsigned short><<<dim3(64, 8), 256, 0, stream>>>(
        weighted, HEADS * DIM, DIM, wv_bf, DIM, HD, bv, ctx, DIM, HD, DIM);
    k_gemm<float><<<dim3(64, 8), 256, 0, stream>>>(
        ctx, DIM, 0, wo_bf, DIM, HD, bo, (float*)d_out, DIM, HD, DIM);
}